// Round 5
// baseline (396.193 us; speedup 1.0000x reference)
//
#include <hip/hip_runtime.h>
#include <hip/hip_bf16.h>
#include <math.h>

typedef unsigned short ushort;
typedef __attribute__((ext_vector_type(4))) float f32x4;
typedef __attribute__((ext_vector_type(8))) short s16x8;
typedef __attribute__((ext_vector_type(4))) short s16x4;
typedef __attribute__((ext_vector_type(4))) ushort u16x4;

#define H_    64
#define W_    64
#define DIM   160
#define HEADS 5
#define KD    32
#define WS    14
#define NTOK  196
#define NWIN  400
#define HIDDEN 640
#define EPS   1e-5f
#define NROW  (NWIN*NTOK)    // 78400
#define BATCH 16
#define L_    (H_*W_)
#define MROW  (BATCH*L_)     // 65536

#if __has_builtin(__builtin_amdgcn_exp2f)
#define EXP2(x) __builtin_amdgcn_exp2f(x)
#else
#define EXP2(x) exp2f(x)
#endif

__device__ __forceinline__ ushort f2bfbits(float f) {
    unsigned u = __float_as_uint(f);
    unsigned r = (u + 0x7fffu + ((u >> 16) & 1u)) >> 16;
    return (ushort)r;
}

// ---------------------------------------------------------------- pre kernel
__global__ __launch_bounds__(256) void pre_kernel(
    const float* __restrict__ qkv_w, const float* __restrict__ proj_w,
    const float* __restrict__ fc1_w, const float* __restrict__ fc2_w,
    const float* __restrict__ conv_w, const float* __restrict__ bn_g,
    const float* __restrict__ abias, const int* __restrict__ bidx,
    ushort* __restrict__ wb, float* __restrict__ cwT,
    float* __restrict__ biasT, int n_off)
{
    const int gid = blockIdx.x * 256 + threadIdx.x;
    if (gid < 19200) {
        float4 v = ((const float4*)qkv_w)[gid];
        u16x4 o = { f2bfbits(v.x), f2bfbits(v.y), f2bfbits(v.z), f2bfbits(v.w) };
        *(u16x4*)(wb + gid * 4) = o;
    } else if (gid < 25600) {
        const int i = gid - 19200;
        float4 v = ((const float4*)proj_w)[i];
        u16x4 o = { f2bfbits(v.x), f2bfbits(v.y), f2bfbits(v.z), f2bfbits(v.w) };
        *(u16x4*)(wb + 76800 + i * 4) = o;
    } else if (gid < 51200) {
        const int i = gid - 25600;
        float4 v = ((const float4*)fc1_w)[i];
        u16x4 o = { f2bfbits(v.x), f2bfbits(v.y), f2bfbits(v.z), f2bfbits(v.w) };
        *(u16x4*)(wb + 102400 + i * 4) = o;
    } else if (gid < 76800) {
        const int i = gid - 51200;
        float4 v = ((const float4*)fc2_w)[i];
        u16x4 o = { f2bfbits(v.x), f2bfbits(v.y), f2bfbits(v.z), f2bfbits(v.w) };
        *(u16x4*)(wb + 204800 + i * 4) = o;
    } else if (gid < 77160) {
        const int i = gid - 76800;
        const int t = i / 40, c4 = (i % 40) * 4;
#pragma unroll
        for (int j = 0; j < 4; ++j) {
            const int c = c4 + j;
            cwT[t * DIM + c] = conv_w[c * 9 + t] * bn_g[c] * rsqrtf(1.0f + EPS);
        }
    } else if (gid < 269240) {
        const int i = gid - 77160;
        const int h = i / (NTOK * NTOK), r = i % (NTOK * NTOK);
        const int q = r / NTOK, k = r % NTOK;
        biasT[i] = abias[h * n_off + bidx[q * NTOK + k]] * 5.656854249492381f;
    }
}

// ---------------------------------------------------------------- LN kernels
__global__ __launch_bounds__(256) void ln1_win_kernel(
    const float* __restrict__ x, const float* __restrict__ g,
    const float* __restrict__ b, ushort* __restrict__ xn)
{
    const int row = blockIdx.x * 4 + (threadIdx.x >> 6);
    const int win = row / NTOK, tok = row % NTOK;
    const int bb = win / 25, wr = (win % 25) / 5, wc = win % 5;
    const int gh = wr * WS + tok / WS, gw = wc * WS + tok % WS;
    const bool valid = (gh < H_) && (gw < W_);
    const float* xrow = x + ((size_t)bb * L_ + (size_t)gh * W_ + gw) * DIM;
    const int lane = threadIdx.x & 63;
    float v0 = 0.f, v1 = 0.f, v2 = 0.f;
    if (valid) {
        v0 = xrow[lane];
        v1 = xrow[lane + 64];
        if (lane < 32) v2 = xrow[lane + 128];
    }
    float s  = v0 + v1 + v2;
    float sq = v0 * v0 + v1 * v1 + v2 * v2;
#pragma unroll
    for (int off = 32; off; off >>= 1) { s += __shfl_xor(s, off); sq += __shfl_xor(sq, off); }
    const float mean = s * (1.0f / DIM);
    const float var  = sq * (1.0f / DIM) - mean * mean;
    const float rs   = rsqrtf(var + EPS);
    ushort* orow = xn + (size_t)row * DIM;
    orow[lane]      = f2bfbits((v0 - mean) * rs * g[lane]      + b[lane]);
    orow[lane + 64] = f2bfbits((v1 - mean) * rs * g[lane + 64] + b[lane + 64]);
    if (lane < 32) orow[lane + 128] = f2bfbits((v2 - mean) * rs * g[lane + 128] + b[lane + 128]);
}

__global__ __launch_bounds__(256) void ln2_kernel(
    const float* __restrict__ x, const float* __restrict__ g,
    const float* __restrict__ b, ushort* __restrict__ xn)
{
    const int row = blockIdx.x * 4 + (threadIdx.x >> 6);
    const float* xrow = x + (size_t)row * DIM;
    const int lane = threadIdx.x & 63;
    float v0 = xrow[lane];
    float v1 = xrow[lane + 64];
    float v2 = (lane < 32) ? xrow[lane + 128] : 0.f;
    float s  = v0 + v1 + v2;
    float sq = v0 * v0 + v1 * v1 + v2 * v2;
#pragma unroll
    for (int off = 32; off; off >>= 1) { s += __shfl_xor(s, off); sq += __shfl_xor(sq, off); }
    const float mean = s * (1.0f / DIM);
    const float var  = sq * (1.0f / DIM) - mean * mean;
    const float rs   = rsqrtf(var + EPS);
    ushort* orow = xn + (size_t)row * DIM;
    orow[lane]      = f2bfbits((v0 - mean) * rs * g[lane]      + b[lane]);
    orow[lane + 64] = f2bfbits((v1 - mean) * rs * g[lane + 64] + b[lane + 64]);
    if (lane < 32) orow[lane + 128] = f2bfbits((v2 - mean) * rs * g[lane + 128] + b[lane + 128]);
}

// ---------------------------------------------------------------- MFMA GEMM
// C[m,n] = sum_k A[m,k] * Wb[n,k] + bias[n].  A, Wb bf16-bits.
// Whole weight panel (160 N x 160 K) staged in LDS ONCE per K-chunk; the
// k-loop then runs with ZERO barriers (A streams global->reg, depth-3
// pipeline). Pitch 164: 18*l15 mod 32 -> 16 distinct banks, reads ~free.
#define GBM 128
#define GBN 160
#define GKC 160

template <int EPI>
__global__ __launch_bounds__(256, 3) void gemm_mfma(
    const ushort* __restrict__ A, const ushort* __restrict__ Wb,
    const float* __restrict__ bias, void* __restrict__ Cv,
    const float* __restrict__ extra, int M, int N, int K)
{
    __shared__ ushort Bs[GBN][164];
    const int tid = threadIdx.x;
    const int wv = tid >> 6, ln = tid & 63;
    const int g = ln >> 4, l15 = ln & 15;
    const int m0 = blockIdx.y * GBM, n0 = blockIdx.x * GBN;
    const int nk = K >> 5;   // 32-wide k-steps
    f32x4 acc[2][10] = {};

    int am0 = m0 + wv * 32 + l15;      if (am0 >= M) am0 = M - 1;
    int am1 = m0 + wv * 32 + 16 + l15; if (am1 >= M) am1 = M - 1;
    const ushort* A0 = A + (size_t)am0 * K + g * 8;
    const ushort* A1 = A + (size_t)am1 * K + g * 8;

    // depth-3 A register pipeline
    s16x8 a0_c = *(const s16x8*)(A0);
    s16x8 a1_c = *(const s16x8*)(A1);
    s16x8 a0_n1 = a0_c, a1_n1 = a1_c, a0_n2 = a0_c, a1_n2 = a1_c;
    if (nk > 1) { a0_n1 = *(const s16x8*)(A0 + 32); a1_n1 = *(const s16x8*)(A1 + 32); }
    if (nk > 2) { a0_n2 = *(const s16x8*)(A0 + 64); a1_n2 = *(const s16x8*)(A1 + 64); }

    int s = 0;
    for (int kc = 0; kc < K; kc += GKC) {
        if (kc) __syncthreads();
        for (int e = tid; e < (GBN * GKC / 8); e += 256) {
            const int row = e / (GKC / 8), part = e % (GKC / 8);
            *(int4*)&Bs[row][part * 8] =
                *(const int4*)(Wb + (size_t)(n0 + row) * K + kc + part * 8);
        }
        __syncthreads();
#pragma unroll
        for (int j = 0; j < GKC / 32; ++j, ++s) {
#pragma unroll
            for (int nt = 0; nt < 10; ++nt) {
                const s16x8 bf = *(const s16x8*)&Bs[nt * 16 + l15][j * 32 + g * 8];
                acc[0][nt] = __builtin_amdgcn_mfma_f32_16x16x32_bf16(a0_c, bf, acc[0][nt], 0, 0, 0);
                acc[1][nt] = __builtin_amdgcn_mfma_f32_16x16x32_bf16(a1_c, bf, acc[1][nt], 0, 0, 0);
            }
            a0_c = a0_n1; a1_c = a1_n1;
            a0_n1 = a0_n2; a1_n1 = a1_n2;
            if (s + 3 < nk) {
                a0_n2 = *(const s16x8*)(A0 + (s + 3) * 32);
                a1_n2 = *(const s16x8*)(A1 + (s + 3) * 32);
            }
        }
    }

#pragma unroll
    for (int mt = 0; mt < 2; ++mt) {
#pragma unroll
        for (int nt = 0; nt < 10; ++nt) {
            const int n = n0 + nt * 16 + l15;
            const float bn = bias[n];
#pragma unroll
            for (int r = 0; r < 4; ++r) {
                const int m = m0 + wv * 32 + mt * 16 + g * 4 + r;
                if (m >= M) continue;
                const float val = acc[mt][nt][r] + bn;
                if (EPI == 0) {
                    ((ushort*)Cv)[(size_t)m * N + n] = f2bfbits(val);
                } else if (EPI == 1) {
                    const int win = m / NTOK, tok = m % NTOK;
                    const int bb = win / 25, wr = (win % 25) / 5, wc = win % 5;
                    const int gh = wr * WS + tok / WS, gw = wc * WS + tok % WS;
                    if (gh < H_ && gw < W_) {
                        const size_t off = ((size_t)bb * L_ + (size_t)gh * W_ + gw) * DIM + n;
                        ((float*)Cv)[off] = extra[off] + val;
                    }
                } else if (EPI == 2) {
                    // tanh-form GELU in exp2 domain (err vs exact erf < 1e-3 on h,
                    // < 2e-4 after fc2): x / (1 + exp2(-2*log2e*c0*(x + c1 x^3)))
                    const float t = EXP2(-2.302259756f * fmaf(0.044715f * val * val, val, val));
                    const float ge = val * __builtin_amdgcn_rcpf(1.0f + t);
                    ((ushort*)Cv)[(size_t)m * N + n] = f2bfbits(ge);
                } else {
                    const size_t off = (size_t)m * N + n;
                    ((float*)Cv)[off] = extra[off] + val;
                }
            }
        }
    }
}

// ---------------------------------------------------------------- attention
__global__ __launch_bounds__(256) void attn_mfma_kernel(
    const ushort* __restrict__ qkv, const float* __restrict__ biasT,
    ushort* __restrict__ out)
{
    __shared__ ushort Ks[208][40];
    __shared__ ushort VT[32][212];
    const int win = blockIdx.x / HEADS;
    const int h   = blockIdx.x % HEADS;
    const int tid = threadIdx.x;
    const size_t base = (size_t)win * NTOK;
    const ushort* qbase = qkv + base * 480 + h * 96;

    for (int e = tid; e < 208 * 4; e += 256) {
        const int row = e >> 2, part = e & 3;
        const int gr = row < NTOK ? row : NTOK - 1;
        *(int4*)&Ks[row][part * 8] = *(const int4*)(qbase + (size_t)gr * 480 + 32 + part * 8);
    }
    for (int e = tid; e < NTOK * 4; e += 256) {
        const int key = e >> 2, part = e & 3;
        int4 p = *(const int4*)(qbase + (size_t)key * 480 + 64 + part * 8);
        const ushort* u = (const ushort*)&p;
#pragma unroll
        for (int j = 0; j < 8; ++j) VT[part * 8 + j][key] = u[j];
    }
    for (int e = tid; e < 12 * 32; e += 256) VT[e & 31][NTOK + (e >> 5)] = 0;
    __syncthreads();

    const int wv = tid >> 6, ln = tid & 63, g = ln >> 4, l15 = ln & 15;
    const float cs = 0.17677669529663687f * 1.4426950408889634f;  // scale*log2e

    for (int qt = wv; qt < 13; qt += 4) {
        const int qr = qt * 16 + l15;
        const int qc = qr < NTOK ? qr : NTOK - 1;
        const s16x8 qf = *(const s16x8*)(qbase + (size_t)qc * 480 + g * 8);
        const float* bq = biasT + ((size_t)h * NTOK + qc) * NTOK;

        f32x4 S[13];
#pragma unroll
        for (int kt = 0; kt < 13; ++kt)
            S[kt] = *(const f32x4*)(bq + kt * 16 + g * 4);
#pragma unroll
        for (int kt = 0; kt < 13; ++kt) {
            const s16x8 kf = *(const s16x8*)&Ks[kt * 16 + l15][g * 8];
            S[kt] = __builtin_amdgcn_mfma_f32_16x16x32_bf16(kf, qf, S[kt], 0, 0, 0);
        }
        float mx = -1e30f;
#pragma unroll
        for (int kt = 0; kt < 13; ++kt) {
            const int kb = kt * 16 + g * 4;
#pragma unroll
            for (int r = 0; r < 4; ++r) {
                const float sv = (kb + r < NTOK) ? S[kt][r] * cs : -1e30f;
                S[kt][r] = sv;
                mx = fmaxf(mx, sv);
            }
        }
        mx = fmaxf(mx, __shfl_xor(mx, 16));
        mx = fmaxf(mx, __shfl_xor(mx, 32));

        float sum = 0.f;
        s16x4 P[13];
#pragma unroll
        for (int kt = 0; kt < 13; ++kt) {
            const float p0 = EXP2(S[kt][0] - mx);
            const float p1 = EXP2(S[kt][1] - mx);
            const float p2 = EXP2(S[kt][2] - mx);
            const float p3 = EXP2(S[kt][3] - mx);
            sum += (p0 + p1) + (p2 + p3);
            P[kt] = (s16x4){ (short)f2bfbits(p0), (short)f2bfbits(p1),
                             (short)f2bfbits(p2), (short)f2bfbits(p3) };
        }
        sum += __shfl_xor(sum, 16);
        sum += __shfl_xor(sum, 32);

        f32x4 o0 = {0.f,0.f,0.f,0.f}, o1 = {0.f,0.f,0.f,0.f};
#pragma unroll
        for (int kt = 0; kt < 13; ++kt) {
            const s16x4 vf0 = *(const s16x4*)&VT[l15][kt * 16 + g * 4];
            const s16x4 vf1 = *(const s16x4*)&VT[16 + l15][kt * 16 + g * 4];
            o0 = __builtin_amdgcn_mfma_f32_16x16x16bf16_1k(vf0, P[kt], o0, 0, 0, 0);
            o1 = __builtin_amdgcn_mfma_f32_16x16x16bf16_1k(vf1, P[kt], o1, 0, 0, 0);
        }
        if (qr < NTOK) {
            const float inv = 1.0f / sum;
            ushort* op = out + (base + qr) * DIM + h * KD;
            u16x4 w0 = { f2bfbits(o0[0] * inv), f2bfbits(o0[1] * inv),
                         f2bfbits(o0[2] * inv), f2bfbits(o0[3] * inv) };
            u16x4 w1 = { f2bfbits(o1[0] * inv), f2bfbits(o1[1] * inv),
                         f2bfbits(o1[2] * inv), f2bfbits(o1[3] * inv) };
            *(u16x4*)(op + g * 4)      = w0;
            *(u16x4*)(op + 16 + g * 4) = w1;
        }
    }
}

// ---------------------------------------------------------------- dw conv + BN
__global__ __launch_bounds__(256) void dwconv_bn_kernel(
    const float* __restrict__ xin, const float* __restrict__ cwT,
    const float* __restrict__ bnb, float* __restrict__ xout)
{
    const int gid = blockIdx.x * 256 + threadIdx.x;   // MROW*40
    const int pos = gid / 40, c4 = (gid % 40) * 4;
    const int bb = pos >> 12, hw = pos & 4095;
    const int hh = hw >> 6, ww = hw & 63;
    float4 acc = *(const float4*)&bnb[c4];
#pragma unroll
    for (int kh = -1; kh <= 1; ++kh) {
        const int ih = hh + kh;
        if (ih < 0 || ih >= H_) continue;
#pragma unroll
        for (int kw = -1; kw <= 1; ++kw) {
            const int iw = ww + kw;
            if (iw < 0 || iw >= W_) continue;
            const float4 xv = *(const float4*)&xin[((size_t)(bb << 12) + (ih << 6) + iw) * DIM + c4];
            const float4 wv = *(const float4*)&cwT[((kh + 1) * 3 + (kw + 1)) * DIM + c4];
            acc.x = fmaf(xv.x, wv.x, acc.x);
            acc.y = fmaf(xv.y, wv.y, acc.y);
            acc.z = fmaf(xv.z, wv.z, acc.z);
            acc.w = fmaf(xv.w, wv.w, acc.w);
        }
    }
    *(float4*)&xout[(size_t)pos * DIM + c4] = acc;
}

// ---------------------------------------------------------------- launch
extern "C" void kernel_launch(void* const* d_in, const int* in_sizes, int n_in,
                              void* d_out, int out_size, void* d_ws, size_t ws_size,
                              hipStream_t stream)
{
    const float* x      = (const float*)d_in[0];
    const float* ln1_g  = (const float*)d_in[1];
    const float* ln1_b  = (const float*)d_in[2];
    const float* qkv_w  = (const float*)d_in[3];
    const float* qkv_b  = (const float*)d_in[4];
    const float* proj_w = (const float*)d_in[5];
    const float* proj_b = (const float*)d_in[6];
    const float* abias  = (const float*)d_in[7];
    const float* conv_w = (const float*)d_in[8];
    const float* bn_g   = (const float*)d_in[9];
    const float* bn_b   = (const float*)d_in[10];
    const float* ln2_g  = (const float*)d_in[11];
    const float* ln2_b  = (const float*)d_in[12];
    const float* fc1_w  = (const float*)d_in[13];
    const float* fc1_b  = (const float*)d_in[14];
    const float* fc2_w  = (const float*)d_in[15];
    const float* fc2_b  = (const float*)d_in[16];
    const int*   bidx   = (const int*)d_in[17];
    const int    n_off  = in_sizes[7] / HEADS;

    char* ws = (char*)d_ws;
    // [0,          25,088,000)  xn  bf16 78400x160   (dead after qkv gemm)
    // [25,088,000, 100,352,000) qkv bf16 78400x480   (dead after attn)
    // [0,          83,886,080)  h   bf16 65536x640   (reuses xn+qkv)
    // [100,352,000,125,440,000) ao  bf16 78400x160   (dead after proj) / xn2
    // [125,440,000,126,208,320) biasT f32 5x196x196  (overlaps x1; attn reads
    //                            it before proj writes x1)
    // [125,440,000,167,383,040) x1  f32 65536x160    (dead after conv)
    // [167,383,040,167,997,440) wb  bf16 weights (qkv|proj|fc1|fc2)
    // [167,997,440,168,003,200) cwT f32 9x160 (BN-folded)
    ushort* xn    = (ushort*)(ws);
    ushort* qkv   = (ushort*)(ws + 25088000);
    ushort* ao    = (ushort*)(ws + 100352000);
    ushort* xn2   = (ushort*)(ws + 100352000);
    float*  biasT = (float*)(ws + 125440000);
    float*  x1    = (float*)(ws + 125440000);
    ushort* hbuf  = (ushort*)(ws);
    ushort* wb    = (ushort*)(ws + 167383040);
    float*  cwT   = (float*)(ws + 167997440);
    float*  x2    = (float*)d_out;
    float*  outp  = (float*)d_out;

    pre_kernel<<<dim3(1052), dim3(256), 0, stream>>>(
        qkv_w, proj_w, fc1_w, fc2_w, conv_w, bn_g, abias, bidx, wb, cwT, biasT, n_off);

    ln1_win_kernel<<<dim3(NROW / 4), dim3(256), 0, stream>>>(x, ln1_g, ln1_b, xn);

    gemm_mfma<0><<<dim3(480 / GBN, (NROW + GBM - 1) / GBM), dim3(256), 0, stream>>>(
        xn, wb, qkv_b, (void*)qkv, nullptr, NROW, 480, DIM);

    attn_mfma_kernel<<<dim3(NWIN * HEADS), dim3(256), 0, stream>>>(qkv, biasT, ao);

    gemm_mfma<1><<<dim3(DIM / GBN, (NROW + GBM - 1) / GBM), dim3(256), 0, stream>>>(
        ao, wb + 76800, proj_b, (void*)x1, x, NROW, DIM, DIM);

    dwconv_bn_kernel<<<dim3(MROW * 40 / 256), dim3(256), 0, stream>>>(
        x1, cwT, bn_b, x2);

    ln2_kernel<<<dim3(MROW / 4), dim3(256), 0, stream>>>(x2, ln2_g, ln2_b, xn2);

    gemm_mfma<2><<<dim3(HIDDEN / GBN, MROW / GBM), dim3(256), 0, stream>>>(
        xn2, wb + 102400, fc1_b, (void*)hbuf, nullptr, MROW, HIDDEN, DIM);

    gemm_mfma<3><<<dim3(DIM / GBN, MROW / GBM), dim3(256), 0, stream>>>(
        hbuf, wb + 204800, fc2_b, (void*)outp, x2, MROW, DIM, HIDDEN);
}